// Round 5
// baseline (136.323 us; speedup 1.0000x reference)
//
#include <hip/hip_runtime.h>

#define NROW   1024
#define ROWLEN 9216
#define NGRP   1024
#define NT     256
#define GPT    4            // groups per thread; thread owns 36 consecutive floats
#define LCAP   256          // boundary-bucket list capacity

__device__ __forceinline__ int bucketOf(float v) {   // monotone, equal v -> equal bucket
    int b = (int)(v * 256.0f);
    return b > 255 ? 255 : b;
}

// full pass-1 replay for one group (cold fallback path only)
__device__ void replay_group(const float* wg, float scale, float zp,
                             float r[9], float err[9], float q[9],
                             int* nflip1, bool* isup1, int* li_out) {
    float pri[9];
    #pragma unroll
    for (int j = 0; j < 9; ++j) {
        float qq = __fsub_rn(__fmul_rn(scale, wg[j]), zp);
        float rr = rintf(qq);
        q[j] = qq; r[j] = rr; err[j] = __fsub_rn(rr, qq);
    }
    float e = __fadd_rn(
                __fadd_rn(__fadd_rn(__fadd_rn(err[0], err[1]), __fadd_rn(err[2], err[3])),
                          __fadd_rn(__fadd_rn(err[4], err[5]), __fadd_rn(err[6], err[7]))),
                err[8]);
    int nf0 = (int)rintf(fabsf(e));
    bool up = (e < 0.0f);
    #pragma unroll
    for (int j = 0; j < 9; ++j) {
        bool cand = up ? ((err[j] < 0.0f) && (q[j] < 7.0f))
                       : ((err[j] > 0.0f) && (q[j] > -8.0f));
        pri[j] = cand ? (up ? -err[j] : err[j]) : 0.0f;
    }
    int rank[9] = {0,0,0,0,0,0,0,0,0};
    #pragma unroll
    for (int a = 0; a < 9; ++a)
        #pragma unroll
        for (int b = a + 1; b < 9; ++b) {
            int c = (pri[a] >= pri[b]) ? 1 : 0;
            rank[b] += c; rank[a] += 1 - c;
        }
    int nf = nf0 < 9 ? nf0 : 9;
    int lip = nf - 1; if (lip < 0) lip = 0;
    int li = 0;
    #pragma unroll
    for (int j = 0; j < 9; ++j) if (rank[j] == lip) li = j;
    *nflip1 = nf0; *isup1 = up; *li_out = li;
}

__global__ __launch_bounds__(NT, 4) void squant_kernel(const float* __restrict__ w,
                                                       float* __restrict__ out) {
    __shared__ alignas(16) signed char s_r2[ROWLEN];  //  9216 B
    __shared__ unsigned short s_upos[NGRP];           //  2048 B
    __shared__ unsigned short s_dpos[NGRP];           //  2048 B
    __shared__ float s_uval[NGRP];                    //  4096 B
    __shared__ float s_dval[NGRP];                    //  4096 B
    __shared__ signed char s_ucn[NGRP];               //  1024 B
    __shared__ signed char s_dcn[NGRP];               //  1024 B
    __shared__ float s_leaf[128];                     //   512 B
    __shared__ int   s_hist[256];                     //  1024 B
    __shared__ float s_lv[LCAP];                      //  1024 B
    __shared__ unsigned short s_lg[LCAP];             //   512 B
    __shared__ float s_wred[8];
    __shared__ float s_bc[2];
    __shared__ float s_e2s;
    __shared__ int   s_seli[2];
    __shared__ int   s_lcount;                        // total ~26.8 KB

    const int row = blockIdx.x;
    const int tid = threadIdx.x;
    const int lane = tid & 63, wid = tid >> 6;
    const float* wrow = w + (size_t)row * ROWLEN;

    // ---------- Phase A: load own 36 floats into REGISTERS + row min/max ----------
    float fe[36];                                     // w values; overwritten with err2
    float vmin =  3.402823466e38f;
    float vmax = -3.402823466e38f;
    const float4* wt4 = reinterpret_cast<const float4*>(wrow + 36 * tid);
    #pragma unroll
    for (int k = 0; k < 9; ++k) {
        float4 v = wt4[k];
        fe[4*k+0] = v.x; fe[4*k+1] = v.y; fe[4*k+2] = v.z; fe[4*k+3] = v.w;
        vmin = fminf(vmin, fminf(fminf(v.x, v.y), fminf(v.z, v.w)));
        vmax = fmaxf(vmax, fmaxf(fmaxf(v.x, v.y), fmaxf(v.z, v.w)));
    }
    #pragma unroll
    for (int o = 32; o > 0; o >>= 1) {
        vmin = fminf(vmin, __shfl_xor(vmin, o, 64));
        vmax = fmaxf(vmax, __shfl_xor(vmax, o, 64));
    }
    if (lane == 0) { s_wred[wid] = vmin; s_wred[4 + wid] = vmax; }
    __syncthreads();
    if (tid == 0) {
        float a = s_wred[0], b = s_wred[4];
        #pragma unroll
        for (int i = 1; i < 4; ++i) { a = fminf(a, s_wred[i]); b = fmaxf(b, s_wred[4 + i]); }
        s_bc[0] = a; s_bc[1] = b;
    }
    __syncthreads();
    const float scale = __fdiv_rn(15.0f, fmaxf(__fsub_rn(s_bc[1], s_bc[0]), 1e-8f));
    const float zp    = __fadd_rn(rintf(__fmul_rn(scale, s_bc[0])), 8.0f);

    // ---------- Phase B: pass 1, fully register-resident ----------
    int pk[9] = {0,0,0,0,0,0,0,0,0};                  // 36 packed r2 bytes
    #pragma unroll
    for (int gi = 0; gi < GPT; ++gi) {
        const int g = tid * GPT + gi;
        const int base = g * 9;
        float q[9], r[9], err[9], pri[9];
        #pragma unroll
        for (int j = 0; j < 9; ++j) {
            float wv = fe[9 * gi + j];
            float qq = __fsub_rn(__fmul_rn(scale, wv), zp);  // no fma: numpy mul-then-sub
            float rr = rintf(qq);                              // half-even == np.round
            q[j] = qq; r[j] = rr; err[j] = __fsub_rn(rr, qq);
        }
        float e = __fadd_rn(
                    __fadd_rn(__fadd_rn(__fadd_rn(err[0], err[1]), __fadd_rn(err[2], err[3])),
                              __fadd_rn(__fadd_rn(err[4], err[5]), __fadd_rn(err[6], err[7]))),
                    err[8]);
        int nflip = (int)rintf(fabsf(e));
        const bool isup = (e < 0.0f);
        #pragma unroll
        for (int j = 0; j < 9; ++j) {
            bool cand = isup ? ((err[j] < 0.0f) && (q[j] < 7.0f))
                             : ((err[j] > 0.0f) && (q[j] > -8.0f));
            pri[j] = cand ? (isup ? -err[j] : err[j]) : 0.0f;   // cand <=> pri>0
        }
        int rank[9] = {0,0,0,0,0,0,0,0,0};
        #pragma unroll
        for (int a = 0; a < 9; ++a)
            #pragma unroll
            for (int b = a + 1; b < 9; ++b) {
                int c = (pri[a] >= pri[b]) ? 1 : 0;
                rank[b] += c; rank[a] += 1 - c;
            }
        const int nf  = nflip < 9 ? nflip : 9;
        const int nip = nf < 8 ? nf : 8;
        int lip = nf - 1; if (lip < 0) lip = 0;

        int ni = 0, li = 0;
        float pri_ni = 0.0f, pri_li = 0.0f, r_ni = 0.0f, r_li = 0.0f;
        #pragma unroll
        for (int j = 0; j < 9; ++j) {
            bool cand = pri[j] > 0.0f;
            bool flip = rank[j] < nf;
            float cnj = cand ? (isup ? r[j] + 1.0f : r[j] - 1.0f) : r[j];
            float cej = cand ? (isup ? __fadd_rn(err[j], 1.0f) : __fsub_rn(err[j], 1.0f)) : 0.0f;
            fe[9 * gi + j] = flip ? cej : err[j];      // register slot: w -> err2
            int enc = __float2int_rn(flip ? cnj : r[j]) & 0xff;
            const int m = 9 * gi + j;                  // compile-time constant
            pk[m >> 2] |= enc << (8 * (m & 3));
            if (rank[j] == nip) { ni = j; pri_ni = pri[j]; r_ni = r[j]; }
            if (rank[j] == lip) { li = j; pri_li = pri[j]; r_li = r[j]; }
        }
        const bool has_next = (nflip < 9);
        const bool has_last = (nflip > 0);
        const float next_pri = has_next ? pri_ni : 0.0f;
        const float last_pri = has_last ? __fsub_rn(1.0f, pri_li) : 0.0f;
        signed char ncv = (signed char)__float2int_rn(
            (pri_ni > 0.0f) ? (isup ? r_ni + 1.0f : r_ni - 1.0f) : r_ni);
        signed char lcv = (signed char)__float2int_rn(r_li);
        if (isup) {
            s_upos[g] = (unsigned short)(base + ni); s_uval[g] = next_pri; s_ucn[g] = ncv;
            s_dpos[g] = (unsigned short)(base + li); s_dval[g] = last_pri; s_dcn[g] = lcv;
        } else {
            s_dpos[g] = (unsigned short)(base + ni); s_dval[g] = next_pri; s_dcn[g] = ncv;
            s_upos[g] = (unsigned short)(base + li); s_uval[g] = last_pri; s_ucn[g] = lcv;
        }
    }
    {   // write packed r2: 9 dwords/thread, lane stride 9 words (<=2-way aliasing = free)
        int* r2w = reinterpret_cast<int*>(s_r2);
        #pragma unroll
        for (int k = 0; k < 9; ++k) r2w[9 * tid + k] = pk[k];
    }

    // ---------- e2: numpy f32 pairwise sum; leaf(72) = even-half + odd-half chains ----------
    {
        const int h = tid & 1;
        // prefix chains over own 36 err2 values (acc j: global elements 8i+j, i ascending)
        float pe[8];
        #pragma unroll
        for (int j = 0; j < 8; ++j) {
            float s = __fadd_rn(__fadd_rn(__fadd_rn(fe[j], fe[8 + j]), fe[16 + j]), fe[24 + j]);
            if (j < 4) s = __fadd_rn(s, fe[32 + j]);
            pe[j] = s;
        }
        #pragma unroll
        for (int j = 0; j < 8; ++j) pe[j] = __shfl_xor(pe[j], 1, 64);  // odd gets even's prefix
        float po[8];
        #pragma unroll
        for (int j = 0; j < 4; ++j)
            po[j] = __fadd_rn(__fadd_rn(__fadd_rn(__fadd_rn(pe[j], fe[4 + j]),
                                                  fe[12 + j]), fe[20 + j]), fe[28 + j]);
        #pragma unroll
        for (int j = 4; j < 8; ++j)
            po[j] = __fadd_rn(__fadd_rn(__fadd_rn(__fadd_rn(__fadd_rn(pe[j], fe[j - 4]),
                                                  fe[4 + j]), fe[12 + j]), fe[20 + j]), fe[28 + j]);
        float res = __fadd_rn(__fadd_rn(__fadd_rn(po[0], po[1]), __fadd_rn(po[2], po[3])),
                              __fadd_rn(__fadd_rn(po[4], po[5]), __fadd_rn(po[6], po[7])));
        if (h) s_leaf[tid >> 1] = res;
        s_hist[tid] = 0;
        if (tid == 0) s_lcount = 0;
    }
    __syncthreads();
    if (tid < 64) {                                   // exact balanced tree over 128 leaves
        float v = __fadd_rn(s_leaf[2 * tid], s_leaf[2 * tid + 1]);
        #pragma unroll
        for (int o = 1; o < 64; o <<= 1) {
            float u = __shfl_xor(v, o, 64);
            v = __fadd_rn(v, u);
        }
        if (tid == 0) s_e2s = v;
    }
    __syncthreads();

    const float e2     = s_e2s;
    const int   nflip2 = (int)rintf(fabsf(e2));
    const bool  isup2  = (e2 < 0.0f);
    const float* val = isup2 ? s_uval : s_dval;
    const unsigned short* pos = isup2 ? s_upos : s_dpos;
    const signed char* cnv = isup2 ? s_ucn : s_dcn;

    // ---------- Phase C: stable top-nflip2 via 256-bucket histogram select ----------
    int   gg[4]; float vv[4]; int bb[4];
    #pragma unroll
    for (int m = 0; m < 4; ++m) {
        gg[m] = tid + m * NT;
        vv[m] = val[gg[m]];
        bb[m] = (vv[m] > 0.0f) ? bucketOf(vv[m]) : -1;
        if (bb[m] >= 0) atomicAdd(&s_hist[bb[m]], 1);
    }
    __syncthreads();
    if (tid < 64) {                                   // wave suffix scan of 256 bins
        int b0 = s_hist[4*tid], b1 = s_hist[4*tid+1], b2 = s_hist[4*tid+2], b3 = s_hist[4*tid+3];
        int s3 = b3, s2 = b2 + s3, s1 = b1 + s2, s0 = b0 + s1;
        int suf = s0;
        #pragma unroll
        for (int off = 1; off < 64; off <<= 1) {
            int o = __shfl_down(suf, off, 64);
            if (tid + off < 64) suf += o;
        }
        int above = suf - s0;
        s_hist[4*tid]   = s0 + above;
        s_hist[4*tid+1] = s1 + above;
        s_hist[4*tid+2] = s2 + above;
        s_hist[4*tid+3] = s3 + above;
    }
    __syncthreads();
    const int npos = s_hist[0];

    if (nflip2 > 0 && nflip2 <= npos) {
        {                                             // unique cutoff bucket
            int Tb  = s_hist[tid];
            int Tb1 = (tid < 255) ? s_hist[tid + 1] : 0;
            if (Tb >= nflip2 && Tb1 < nflip2) { s_seli[0] = tid; s_seli[1] = nflip2 - Tb1; }
        }
        __syncthreads();
        const int B = s_seli[0], m = s_seli[1];
        #pragma unroll
        for (int mm = 0; mm < 4; ++mm) {
            if (bb[mm] > B) s_r2[pos[gg[mm]]] = cnv[gg[mm]];
            else if (bb[mm] == B) {
                int ix = atomicAdd(&s_lcount, 1);
                if (ix < LCAP) { s_lv[ix] = vv[mm]; s_lg[ix] = (unsigned short)gg[mm]; }
            }
        }
        __syncthreads();
        const int L = s_lcount;
        if (L <= LCAP) {                              // exact stable rank in boundary bucket
            #pragma unroll
            for (int mm = 0; mm < 4; ++mm) {
                if (bb[mm] != B) continue;
                int rk = 0;
                for (int l = 0; l < L; ++l) {
                    float lv = s_lv[l]; int lg = s_lg[l];
                    rk += (int)((lv > vv[mm]) || ((lv == vv[mm]) && (lg < gg[mm])));
                }
                if (rk < m) s_r2[pos[gg[mm]]] = cnv[gg[mm]];
            }
        } else {                                      // degenerate tie flood
            #pragma unroll
            for (int mm = 0; mm < 4; ++mm) {
                if (bb[mm] != B) continue;
                int rk = 0;
                for (int j = 0; j < NGRP; ++j) {
                    float vj = val[j];
                    if (vj > 0.0f && bucketOf(vj) == B)
                        rk += (int)((vj > vv[mm]) || ((vj == vv[mm]) && (j < gg[mm])));
                }
                if (rk < m) s_r2[pos[gg[mm]]] = cnv[gg[mm]];
            }
        }
    } else if (nflip2 > npos) {
        // all positives flip; remainder spills into zero-priority dense slots by index
        #pragma unroll
        for (int mm = 0; mm < 4; ++mm)
            if (bb[mm] >= 0) s_r2[pos[gg[mm]]] = cnv[gg[mm]];
        __syncthreads();
        if (tid == 0) {
            int c = 0; const int extra = nflip2 - npos;
            for (int g = 0; g < NGRP && c < extra; ++g) {
                float r[9], err[9], q[9]; int nf1; bool up1; int li;
                replay_group(wrow + 9 * g, scale, zp, r, err, q, &nf1, &up1, &li);
                for (int j = 0; j < 9 && c < extra; ++j) {
                    int p = 9 * g + j;
                    if (val[g] > 0.0f && pos[g] == p) continue;   // already flipped above
                    float cnp;
                    if (isup2) { bool cu = (err[j] < 0.0f) && (q[j] < 7.0f);
                                 cnp = cu ? r[j] + 1.0f : r[j]; }
                    else       { bool cd = (err[j] > 0.0f) && (q[j] > -8.0f);
                                 cnp = cd ? r[j] - 1.0f : r[j]; }
                    if (nf1 > 0 && j == li && (up1 != isup2)) cnp = r[j];  // pass-1 revert
                    s_r2[p] = (signed char)__float2int_rn(cnp);
                    ++c;
                }
            }
        }
    }
    __syncthreads();

    // ---------- epilogue: clip + dequantize + fp32 store ----------
    const int* r2i = reinterpret_cast<const int*>(s_r2);
    float4* o4 = reinterpret_cast<float4*>(out + (size_t)row * ROWLEN);
    #pragma unroll
    for (int k = 0; k < 9; ++k) {
        int i = tid + k * NT;
        int word = r2i[i];
        float4 o;
        #pragma unroll
        for (int c = 0; c < 4; ++c) {
            int v = (int)(signed char)((word >> (8 * c)) & 0xff);
            v = v < -8 ? -8 : (v > 7 ? 7 : v);
            float f = __fdiv_rn(__fadd_rn((float)v, zp), scale);
            if (c == 0) o.x = f; else if (c == 1) o.y = f; else if (c == 2) o.z = f; else o.w = f;
        }
        o4[i] = o;
    }
}

extern "C" void kernel_launch(void* const* d_in, const int* in_sizes, int n_in,
                              void* d_out, int out_size, void* d_ws, size_t ws_size,
                              hipStream_t stream) {
    const float* w = (const float*)d_in[0];
    float* out = (float*)d_out;
    squant_kernel<<<dim3(NROW), dim3(NT), 0, stream>>>(w, out);
}

// Round 6
// 103.686 us; speedup vs baseline: 1.3148x; 1.3148x over previous
//
#include <hip/hip_runtime.h>

#define NROW   1024
#define ROWLEN 9216
#define NGRP   1024
#define NT     256
#define GPT    4            // groups per thread; thread owns 36 consecutive floats
#define LCAP   256          // boundary-bucket list capacity

__device__ __forceinline__ int bucketOf(float v) {   // monotone, equal v -> equal bucket
    int b = (int)(v * 256.0f);
    return b > 255 ? 255 : b;
}

// full pass-1 replay for one group (cold fallback path only)
__device__ void replay_group(const float* wg, float scale, float zp,
                             float r[9], float err[9], float q[9],
                             int* nflip1, bool* isup1, int* li_out) {
    float pri[9];
    #pragma unroll
    for (int j = 0; j < 9; ++j) {
        float qq = __fsub_rn(__fmul_rn(scale, wg[j]), zp);
        float rr = rintf(qq);
        q[j] = qq; r[j] = rr; err[j] = __fsub_rn(rr, qq);
    }
    float e = __fadd_rn(
                __fadd_rn(__fadd_rn(__fadd_rn(err[0], err[1]), __fadd_rn(err[2], err[3])),
                          __fadd_rn(__fadd_rn(err[4], err[5]), __fadd_rn(err[6], err[7]))),
                err[8]);
    int nf0 = (int)rintf(fabsf(e));
    bool up = (e < 0.0f);
    #pragma unroll
    for (int j = 0; j < 9; ++j) {
        bool cand = up ? ((err[j] < 0.0f) && (q[j] < 7.0f))
                       : ((err[j] > 0.0f) && (q[j] > -8.0f));
        pri[j] = cand ? (up ? -err[j] : err[j]) : 0.0f;
    }
    int rank[9] = {0,0,0,0,0,0,0,0,0};
    #pragma unroll
    for (int a = 0; a < 9; ++a)
        #pragma unroll
        for (int b = a + 1; b < 9; ++b) {
            int c = (pri[a] >= pri[b]) ? 1 : 0;
            rank[b] += c; rank[a] += 1 - c;
        }
    int nf = nf0 < 9 ? nf0 : 9;
    int lip = nf - 1; if (lip < 0) lip = 0;
    int li = 0;
    #pragma unroll
    for (int j = 0; j < 9; ++j) if (rank[j] == lip) li = j;
    *nflip1 = nf0; *isup1 = up; *li_out = li;
}

__global__ __launch_bounds__(NT)
__attribute__((amdgpu_waves_per_eu(4, 4)))   // pin 4 waves/EU -> 128-VGPR budget, no spill
void squant_kernel(const float* __restrict__ w, float* __restrict__ out) {
    __shared__ alignas(16) signed char s_r2[ROWLEN];  //  9216 B
    __shared__ unsigned short s_upos[NGRP];           //  2048 B
    __shared__ unsigned short s_dpos[NGRP];           //  2048 B
    __shared__ float s_uval[NGRP];                    //  4096 B
    __shared__ float s_dval[NGRP];                    //  4096 B
    __shared__ signed char s_ucn[NGRP];               //  1024 B
    __shared__ signed char s_dcn[NGRP];               //  1024 B
    __shared__ float s_leaf[128];                     //   512 B
    __shared__ int   s_hist[256];                     //  1024 B
    __shared__ float s_lv[LCAP];                      //  1024 B
    __shared__ unsigned short s_lg[LCAP];             //   512 B
    __shared__ float s_wred[8];
    __shared__ float s_bc[2];
    __shared__ float s_e2s;
    __shared__ int   s_seli[2];
    __shared__ int   s_lcount;                        // total ~26.8 KB

    const int row = blockIdx.x;
    const int tid = threadIdx.x;
    const int lane = tid & 63, wid = tid >> 6;
    const float* wrow = w + (size_t)row * ROWLEN;

    // ---------- Phase A: load own 36 floats into REGISTERS + row min/max ----------
    float fe[36];                                     // w values; overwritten with err2
    float vmin =  3.402823466e38f;
    float vmax = -3.402823466e38f;
    const float4* wt4 = reinterpret_cast<const float4*>(wrow + 36 * tid);
    #pragma unroll
    for (int k = 0; k < 9; ++k) {
        float4 v = wt4[k];
        fe[4*k+0] = v.x; fe[4*k+1] = v.y; fe[4*k+2] = v.z; fe[4*k+3] = v.w;
        vmin = fminf(vmin, fminf(fminf(v.x, v.y), fminf(v.z, v.w)));
        vmax = fmaxf(vmax, fmaxf(fmaxf(v.x, v.y), fmaxf(v.z, v.w)));
    }
    #pragma unroll
    for (int o = 32; o > 0; o >>= 1) {
        vmin = fminf(vmin, __shfl_xor(vmin, o, 64));
        vmax = fmaxf(vmax, __shfl_xor(vmax, o, 64));
    }
    if (lane == 0) { s_wred[wid] = vmin; s_wred[4 + wid] = vmax; }
    __syncthreads();
    if (tid == 0) {
        float a = s_wred[0], b = s_wred[4];
        #pragma unroll
        for (int i = 1; i < 4; ++i) { a = fminf(a, s_wred[i]); b = fmaxf(b, s_wred[4 + i]); }
        s_bc[0] = a; s_bc[1] = b;
    }
    __syncthreads();
    const float scale = __fdiv_rn(15.0f, fmaxf(__fsub_rn(s_bc[1], s_bc[0]), 1e-8f));
    const float zp    = __fadd_rn(rintf(__fmul_rn(scale, s_bc[0])), 8.0f);

    // ---------- Phase B: pass 1, fully register-resident; r2 bytes -> LDS inline ----------
    #pragma unroll
    for (int gi = 0; gi < GPT; ++gi) {
        const int g = tid * GPT + gi;
        const int base = g * 9;
        float q[9], r[9], err[9], pri[9];
        #pragma unroll
        for (int j = 0; j < 9; ++j) {
            float wv = fe[9 * gi + j];
            float qq = __fsub_rn(__fmul_rn(scale, wv), zp);  // no fma: numpy mul-then-sub
            float rr = rintf(qq);                              // half-even == np.round
            q[j] = qq; r[j] = rr; err[j] = __fsub_rn(rr, qq);
        }
        float e = __fadd_rn(
                    __fadd_rn(__fadd_rn(__fadd_rn(err[0], err[1]), __fadd_rn(err[2], err[3])),
                              __fadd_rn(__fadd_rn(err[4], err[5]), __fadd_rn(err[6], err[7]))),
                    err[8]);
        int nflip = (int)rintf(fabsf(e));
        const bool isup = (e < 0.0f);
        #pragma unroll
        for (int j = 0; j < 9; ++j) {
            bool cand = isup ? ((err[j] < 0.0f) && (q[j] < 7.0f))
                             : ((err[j] > 0.0f) && (q[j] > -8.0f));
            pri[j] = cand ? (isup ? -err[j] : err[j]) : 0.0f;   // cand <=> pri>0
        }
        int rank[9] = {0,0,0,0,0,0,0,0,0};
        #pragma unroll
        for (int a = 0; a < 9; ++a)
            #pragma unroll
            for (int b = a + 1; b < 9; ++b) {
                int c = (pri[a] >= pri[b]) ? 1 : 0;
                rank[b] += c; rank[a] += 1 - c;
            }
        const int nf  = nflip < 9 ? nflip : 9;
        const int nip = nf < 8 ? nf : 8;
        int lip = nf - 1; if (lip < 0) lip = 0;

        int ni = 0, li = 0;
        float pri_ni = 0.0f, pri_li = 0.0f, r_ni = 0.0f, r_li = 0.0f;
        #pragma unroll
        for (int j = 0; j < 9; ++j) {
            bool cand = pri[j] > 0.0f;
            bool flip = rank[j] < nf;
            float cnj = cand ? (isup ? r[j] + 1.0f : r[j] - 1.0f) : r[j];
            float cej = cand ? (isup ? __fadd_rn(err[j], 1.0f) : __fsub_rn(err[j], 1.0f)) : 0.0f;
            fe[9 * gi + j] = flip ? cej : err[j];      // register slot: w -> err2
            s_r2[base + j] = (signed char)__float2int_rn(flip ? cnj : r[j]);
            if (rank[j] == nip) { ni = j; pri_ni = pri[j]; r_ni = r[j]; }
            if (rank[j] == lip) { li = j; pri_li = pri[j]; r_li = r[j]; }
        }
        const bool has_next = (nflip < 9);
        const bool has_last = (nflip > 0);
        const float next_pri = has_next ? pri_ni : 0.0f;
        const float last_pri = has_last ? __fsub_rn(1.0f, pri_li) : 0.0f;
        signed char ncv = (signed char)__float2int_rn(
            (pri_ni > 0.0f) ? (isup ? r_ni + 1.0f : r_ni - 1.0f) : r_ni);
        signed char lcv = (signed char)__float2int_rn(r_li);
        if (isup) {
            s_upos[g] = (unsigned short)(base + ni); s_uval[g] = next_pri; s_ucn[g] = ncv;
            s_dpos[g] = (unsigned short)(base + li); s_dval[g] = last_pri; s_dcn[g] = lcv;
        } else {
            s_dpos[g] = (unsigned short)(base + ni); s_dval[g] = next_pri; s_dcn[g] = ncv;
            s_upos[g] = (unsigned short)(base + li); s_uval[g] = last_pri; s_ucn[g] = lcv;
        }
    }

    // ---------- e2: numpy f32 pairwise sum; leaf(72) = even-half + odd-half chains ----------
    {
        const int h = tid & 1;
        // prefix chains over own 36 err2 values (acc j: leaf-local elements 8i+j, i ascending)
        float pe[8];
        #pragma unroll
        for (int j = 0; j < 8; ++j) {
            float s = __fadd_rn(__fadd_rn(__fadd_rn(fe[j], fe[8 + j]), fe[16 + j]), fe[24 + j]);
            if (j < 4) s = __fadd_rn(s, fe[32 + j]);
            pe[j] = s;
        }
        #pragma unroll
        for (int j = 0; j < 8; ++j) pe[j] = __shfl_xor(pe[j], 1, 64);  // odd gets even's prefix
        float po[8];
        #pragma unroll
        for (int j = 0; j < 4; ++j)
            po[j] = __fadd_rn(__fadd_rn(__fadd_rn(__fadd_rn(pe[j], fe[4 + j]),
                                                  fe[12 + j]), fe[20 + j]), fe[28 + j]);
        #pragma unroll
        for (int j = 4; j < 8; ++j)
            po[j] = __fadd_rn(__fadd_rn(__fadd_rn(__fadd_rn(__fadd_rn(pe[j], fe[j - 4]),
                                                  fe[4 + j]), fe[12 + j]), fe[20 + j]), fe[28 + j]);
        float res = __fadd_rn(__fadd_rn(__fadd_rn(po[0], po[1]), __fadd_rn(po[2], po[3])),
                              __fadd_rn(__fadd_rn(po[4], po[5]), __fadd_rn(po[6], po[7])));
        if (h) s_leaf[tid >> 1] = res;
        s_hist[tid] = 0;
        if (tid == 0) s_lcount = 0;
    }
    __syncthreads();
    if (tid < 64) {                                   // exact balanced tree over 128 leaves
        float v = __fadd_rn(s_leaf[2 * tid], s_leaf[2 * tid + 1]);
        #pragma unroll
        for (int o = 1; o < 64; o <<= 1) {
            float u = __shfl_xor(v, o, 64);
            v = __fadd_rn(v, u);
        }
        if (tid == 0) s_e2s = v;
    }
    __syncthreads();

    const float e2     = s_e2s;
    const int   nflip2 = (int)rintf(fabsf(e2));
    const bool  isup2  = (e2 < 0.0f);
    const float* val = isup2 ? s_uval : s_dval;
    const unsigned short* pos = isup2 ? s_upos : s_dpos;
    const signed char* cnv = isup2 ? s_ucn : s_dcn;

    // ---------- Phase C: stable top-nflip2 via 256-bucket histogram select ----------
    int   gg[4]; float vv[4]; int bb[4];
    #pragma unroll
    for (int m = 0; m < 4; ++m) {
        gg[m] = tid + m * NT;
        vv[m] = val[gg[m]];
        bb[m] = (vv[m] > 0.0f) ? bucketOf(vv[m]) : -1;
        if (bb[m] >= 0) atomicAdd(&s_hist[bb[m]], 1);
    }
    __syncthreads();
    if (tid < 64) {                                   // wave suffix scan of 256 bins
        int b0 = s_hist[4*tid], b1 = s_hist[4*tid+1], b2 = s_hist[4*tid+2], b3 = s_hist[4*tid+3];
        int s3 = b3, s2 = b2 + s3, s1 = b1 + s2, s0 = b0 + s1;
        int suf = s0;
        #pragma unroll
        for (int off = 1; off < 64; off <<= 1) {
            int o = __shfl_down(suf, off, 64);
            if (tid + off < 64) suf += o;
        }
        int above = suf - s0;
        s_hist[4*tid]   = s0 + above;
        s_hist[4*tid+1] = s1 + above;
        s_hist[4*tid+2] = s2 + above;
        s_hist[4*tid+3] = s3 + above;
    }
    __syncthreads();
    const int npos = s_hist[0];

    if (nflip2 > 0 && nflip2 <= npos) {
        {                                             // unique cutoff bucket
            int Tb  = s_hist[tid];
            int Tb1 = (tid < 255) ? s_hist[tid + 1] : 0;
            if (Tb >= nflip2 && Tb1 < nflip2) { s_seli[0] = tid; s_seli[1] = nflip2 - Tb1; }
        }
        __syncthreads();
        const int B = s_seli[0], m = s_seli[1];
        #pragma unroll
        for (int mm = 0; mm < 4; ++mm) {
            if (bb[mm] > B) s_r2[pos[gg[mm]]] = cnv[gg[mm]];
            else if (bb[mm] == B) {
                int ix = atomicAdd(&s_lcount, 1);
                if (ix < LCAP) { s_lv[ix] = vv[mm]; s_lg[ix] = (unsigned short)gg[mm]; }
            }
        }
        __syncthreads();
        const int L = s_lcount;
        if (L <= LCAP) {                              // exact stable rank in boundary bucket
            #pragma unroll
            for (int mm = 0; mm < 4; ++mm) {
                if (bb[mm] != B) continue;
                int rk = 0;
                for (int l = 0; l < L; ++l) {
                    float lv = s_lv[l]; int lg = s_lg[l];
                    rk += (int)((lv > vv[mm]) || ((lv == vv[mm]) && (lg < gg[mm])));
                }
                if (rk < m) s_r2[pos[gg[mm]]] = cnv[gg[mm]];
            }
        } else {                                      // degenerate tie flood
            #pragma unroll
            for (int mm = 0; mm < 4; ++mm) {
                if (bb[mm] != B) continue;
                int rk = 0;
                for (int j = 0; j < NGRP; ++j) {
                    float vj = val[j];
                    if (vj > 0.0f && bucketOf(vj) == B)
                        rk += (int)((vj > vv[mm]) || ((vj == vv[mm]) && (j < gg[mm])));
                }
                if (rk < m) s_r2[pos[gg[mm]]] = cnv[gg[mm]];
            }
        }
    } else if (nflip2 > npos) {
        // all positives flip; remainder spills into zero-priority dense slots by index
        #pragma unroll
        for (int mm = 0; mm < 4; ++mm)
            if (bb[mm] >= 0) s_r2[pos[gg[mm]]] = cnv[gg[mm]];
        __syncthreads();
        if (tid == 0) {
            int c = 0; const int extra = nflip2 - npos;
            for (int g = 0; g < NGRP && c < extra; ++g) {
                float r[9], err[9], q[9]; int nf1; bool up1; int li;
                replay_group(wrow + 9 * g, scale, zp, r, err, q, &nf1, &up1, &li);
                for (int j = 0; j < 9 && c < extra; ++j) {
                    int p = 9 * g + j;
                    if (val[g] > 0.0f && pos[g] == p) continue;   // already flipped above
                    float cnp;
                    if (isup2) { bool cu = (err[j] < 0.0f) && (q[j] < 7.0f);
                                 cnp = cu ? r[j] + 1.0f : r[j]; }
                    else       { bool cd = (err[j] > 0.0f) && (q[j] > -8.0f);
                                 cnp = cd ? r[j] - 1.0f : r[j]; }
                    if (nf1 > 0 && j == li && (up1 != isup2)) cnp = r[j];  // pass-1 revert
                    s_r2[p] = (signed char)__float2int_rn(cnp);
                    ++c;
                }
            }
        }
    }
    __syncthreads();

    // ---------- epilogue: clip + dequantize + fp32 store ----------
    const int* r2i = reinterpret_cast<const int*>(s_r2);
    float4* o4 = reinterpret_cast<float4*>(out + (size_t)row * ROWLEN);
    #pragma unroll
    for (int k = 0; k < 9; ++k) {
        int i = tid + k * NT;
        int word = r2i[i];
        float4 o;
        #pragma unroll
        for (int c = 0; c < 4; ++c) {
            int v = (int)(signed char)((word >> (8 * c)) & 0xff);
            v = v < -8 ? -8 : (v > 7 ? 7 : v);
            float f = __fdiv_rn(__fadd_rn((float)v, zp), scale);
            if (c == 0) o.x = f; else if (c == 1) o.y = f; else if (c == 2) o.z = f; else o.w = f;
        }
        o4[i] = o;
    }
}

extern "C" void kernel_launch(void* const* d_in, const int* in_sizes, int n_in,
                              void* d_out, int out_size, void* d_ws, size_t ws_size,
                              hipStream_t stream) {
    const float* w = (const float*)d_in[0];
    float* out = (float*)d_out;
    squant_kernel<<<dim3(NROW), dim3(NT), 0, stream>>>(w, out);
}

// Round 7
// 97.150 us; speedup vs baseline: 1.4032x; 1.0673x over previous
//
#include <hip/hip_runtime.h>

#define NROW   1024
#define ROWLEN 9216
#define NGRP   1024
#define NT     256
#define GPT    4            // groups per thread; thread owns 36 consecutive floats
#define LCAP   256          // boundary-bucket list capacity

__device__ __forceinline__ int bucketOf(float v) {   // monotone, equal v -> equal bucket
    int b = (int)(v * 256.0f);
    return b > 255 ? 255 : b;
}
__device__ __forceinline__ int clip16(int v) { return v < -8 ? -8 : (v > 7 ? 7 : v); }

// full pass-1 replay for one group (cold fallback path only)
__device__ void replay_group(const float* wg, float scale, float zp,
                             float r[9], float err[9], float q[9],
                             int* nflip1, bool* isup1, int* li_out) {
    float pri[9];
    #pragma unroll
    for (int j = 0; j < 9; ++j) {
        float qq = __fsub_rn(__fmul_rn(scale, wg[j]), zp);
        float rr = rintf(qq);
        q[j] = qq; r[j] = rr; err[j] = __fsub_rn(rr, qq);
    }
    float e = __fadd_rn(
                __fadd_rn(__fadd_rn(__fadd_rn(err[0], err[1]), __fadd_rn(err[2], err[3])),
                          __fadd_rn(__fadd_rn(err[4], err[5]), __fadd_rn(err[6], err[7]))),
                err[8]);
    int nf0 = (int)rintf(fabsf(e));
    bool up = (e < 0.0f);
    #pragma unroll
    for (int j = 0; j < 9; ++j) {
        bool cand = up ? ((err[j] < 0.0f) && (q[j] < 7.0f))
                       : ((err[j] > 0.0f) && (q[j] > -8.0f));
        pri[j] = cand ? (up ? -err[j] : err[j]) : 0.0f;
    }
    int rank[9] = {0,0,0,0,0,0,0,0,0};
    #pragma unroll
    for (int a = 0; a < 9; ++a)
        #pragma unroll
        for (int b = a + 1; b < 9; ++b) {
            int c = (pri[a] >= pri[b]) ? 1 : 0;
            rank[b] += c; rank[a] += 1 - c;
        }
    int nf = nf0 < 9 ? nf0 : 9;
    int lip = nf - 1; if (lip < 0) lip = 0;
    int li = 0;
    #pragma unroll
    for (int j = 0; j < 9; ++j) if (rank[j] == lip) li = j;
    *nflip1 = nf0; *isup1 = up; *li_out = li;
}

__global__ __launch_bounds__(NT)
__attribute__((amdgpu_waves_per_eu(4, 4)))   // pin 4 waves/EU -> 128-VGPR budget, no spill
void squant_kernel(const float* __restrict__ w, float* __restrict__ out) {
    __shared__ alignas(16) signed char s_r2[ROWLEN];  //  9216 B
    __shared__ unsigned short s_upos[NGRP];           //  2048 B
    __shared__ unsigned short s_dpos[NGRP];           //  2048 B
    __shared__ float s_uval[NGRP];                    //  4096 B
    __shared__ float s_dval[NGRP];                    //  4096 B
    __shared__ signed char s_ucn[NGRP];               //  1024 B
    __shared__ signed char s_dcn[NGRP];               //  1024 B
    __shared__ float s_leaf[128];                     //   512 B
    __shared__ int   s_hist[256];                     //  1024 B
    __shared__ float s_lv[LCAP];                      //  1024 B
    __shared__ unsigned short s_lg[LCAP];             //   512 B
    __shared__ float s_lut[16];                       //    64 B  dequant values
    __shared__ float s_wred[8];
    __shared__ float s_bc[2];
    __shared__ float s_e2s;
    __shared__ int   s_seli[2];
    __shared__ int   s_lcount;                        // total ~26.9 KB

    const int row = blockIdx.x;
    const int tid = threadIdx.x;
    const int lane = tid & 63, wid = tid >> 6;
    const float* wrow = w + (size_t)row * ROWLEN;

    // ---------- Phase A: load own 36 floats into REGISTERS + row min/max ----------
    float fe[36];                                     // w values; overwritten with err2
    float vmin =  3.402823466e38f;
    float vmax = -3.402823466e38f;
    const float4* wt4 = reinterpret_cast<const float4*>(wrow + 36 * tid);
    #pragma unroll
    for (int k = 0; k < 9; ++k) {
        float4 v = wt4[k];
        fe[4*k+0] = v.x; fe[4*k+1] = v.y; fe[4*k+2] = v.z; fe[4*k+3] = v.w;
        vmin = fminf(vmin, fminf(fminf(v.x, v.y), fminf(v.z, v.w)));
        vmax = fmaxf(vmax, fmaxf(fmaxf(v.x, v.y), fmaxf(v.z, v.w)));
    }
    #pragma unroll
    for (int o = 32; o > 0; o >>= 1) {
        vmin = fminf(vmin, __shfl_xor(vmin, o, 64));
        vmax = fmaxf(vmax, __shfl_xor(vmax, o, 64));
    }
    if (lane == 0) { s_wred[wid] = vmin; s_wred[4 + wid] = vmax; }
    __syncthreads();
    if (tid == 0) {
        float a = s_wred[0], b = s_wred[4];
        #pragma unroll
        for (int i = 1; i < 4; ++i) { a = fminf(a, s_wred[i]); b = fmaxf(b, s_wred[4 + i]); }
        s_bc[0] = a; s_bc[1] = b;
    }
    __syncthreads();
    const float scale = __fdiv_rn(15.0f, fmaxf(__fsub_rn(s_bc[1], s_bc[0]), 1e-8f));
    const float zp    = __fadd_rn(rintf(__fmul_rn(scale, s_bc[0])), 8.0f);
    // 16 possible dequant outputs; visibility covered by later barriers
    if (tid < 16) s_lut[tid] = __fdiv_rn(__fadd_rn((float)(tid - 8), zp), scale);

    // ---------- Phase B: pass 1, fully register-resident; r2 packed to dwords ----------
    int pk[9] = {0,0,0,0,0,0,0,0,0};                  // 36 packed (pre-clipped) r2 bytes
    #pragma unroll
    for (int gi = 0; gi < GPT; ++gi) {
        const int g = tid * GPT + gi;
        const int base = g * 9;
        float r[9], err[9], pri[9];
        int cu_m = 0, cd_m = 0;
        #pragma unroll
        for (int j = 0; j < 9; ++j) {
            float wv = fe[9 * gi + j];
            float qq = __fsub_rn(__fmul_rn(scale, wv), zp);  // no fma: numpy mul-then-sub
            float rr = rintf(qq);                              // half-even == np.round
            float ee = __fsub_rn(rr, qq);
            r[j] = rr; err[j] = ee;
            if ((ee < 0.0f) && (qq <  7.0f)) cu_m |= (1 << j);
            if ((ee > 0.0f) && (qq > -8.0f)) cd_m |= (1 << j);
        }
        float e = __fadd_rn(
                    __fadd_rn(__fadd_rn(__fadd_rn(err[0], err[1]), __fadd_rn(err[2], err[3])),
                              __fadd_rn(__fadd_rn(err[4], err[5]), __fadd_rn(err[6], err[7]))),
                    err[8]);
        int nflip = (int)rintf(fabsf(e));
        const bool isup = (e < 0.0f);
        const float da = isup ? 1.0f : -1.0f;          // flip delta (exact)
        const int cm = isup ? cu_m : cd_m;
        #pragma unroll
        for (int j = 0; j < 9; ++j)
            pri[j] = ((cm >> j) & 1) ? fabsf(err[j]) : 0.0f;   // cand <=> pri>0
        int rank[9] = {0,0,0,0,0,0,0,0,0};
        #pragma unroll
        for (int a = 0; a < 9; ++a)
            #pragma unroll
            for (int b = a + 1; b < 9; ++b) {
                int c = (pri[a] >= pri[b]) ? 1 : 0;
                rank[b] += c; rank[a] += 1 - c;
            }
        const int nf  = nflip < 9 ? nflip : 9;
        const int nip = nf < 8 ? nf : 8;
        int lip = nf - 1; if (lip < 0) lip = 0;

        int ni = 0, li = 0;
        float pri_ni = 0.0f, pri_li = 0.0f, r_ni = 0.0f, r_li = 0.0f;
        #pragma unroll
        for (int j = 0; j < 9; ++j) {
            bool cand = (cm >> j) & 1;
            bool flip = rank[j] < nf;
            float cnj = cand ? __fadd_rn(r[j], da) : r[j];     // r±1 exact
            float cej = cand ? __fadd_rn(err[j], da) : 0.0f;
            fe[9 * gi + j] = flip ? cej : err[j];      // register slot: w -> err2
            int enc = clip16(__float2int_rn(flip ? cnj : r[j])) & 0xff;
            const int m = 9 * gi + j;                  // compile-time constant
            pk[m >> 2] |= enc << (8 * (m & 3));
            if (rank[j] == nip) { ni = j; pri_ni = pri[j]; r_ni = r[j]; }
            if (rank[j] == lip) { li = j; pri_li = pri[j]; r_li = r[j]; }
        }
        const bool has_next = (nflip < 9);
        const bool has_last = (nflip > 0);
        const float next_pri = has_next ? pri_ni : 0.0f;
        const float last_pri = has_last ? __fsub_rn(1.0f, pri_li) : 0.0f;
        signed char ncv = (signed char)clip16(__float2int_rn(
            (pri_ni > 0.0f) ? __fadd_rn(r_ni, da) : r_ni));
        signed char lcv = (signed char)clip16(__float2int_rn(r_li));
        if (isup) {
            s_upos[g] = (unsigned short)(base + ni); s_uval[g] = next_pri; s_ucn[g] = ncv;
            s_dpos[g] = (unsigned short)(base + li); s_dval[g] = last_pri; s_dcn[g] = lcv;
        } else {
            s_dpos[g] = (unsigned short)(base + ni); s_dval[g] = next_pri; s_dcn[g] = ncv;
            s_upos[g] = (unsigned short)(base + li); s_uval[g] = last_pri; s_ucn[g] = lcv;
        }
    }
    {   // write packed r2: 9 dwords/thread, lane stride 9 words (<=2-way aliasing = free)
        int* r2w = reinterpret_cast<int*>(s_r2);
        #pragma unroll
        for (int k = 0; k < 9; ++k) r2w[9 * tid + k] = pk[k];
    }

    // ---------- e2: numpy f32 pairwise sum; leaf(72) = even-half + odd-half chains ----------
    {
        const int h = tid & 1;
        float pe[8];
        #pragma unroll
        for (int j = 0; j < 8; ++j) {
            float s = __fadd_rn(__fadd_rn(__fadd_rn(fe[j], fe[8 + j]), fe[16 + j]), fe[24 + j]);
            if (j < 4) s = __fadd_rn(s, fe[32 + j]);
            pe[j] = s;
        }
        #pragma unroll
        for (int j = 0; j < 8; ++j) pe[j] = __shfl_xor(pe[j], 1, 64);  // odd gets even's prefix
        float po[8];
        #pragma unroll
        for (int j = 0; j < 4; ++j)
            po[j] = __fadd_rn(__fadd_rn(__fadd_rn(__fadd_rn(pe[j], fe[4 + j]),
                                                  fe[12 + j]), fe[20 + j]), fe[28 + j]);
        #pragma unroll
        for (int j = 4; j < 8; ++j)
            po[j] = __fadd_rn(__fadd_rn(__fadd_rn(__fadd_rn(__fadd_rn(pe[j], fe[j - 4]),
                                                  fe[4 + j]), fe[12 + j]), fe[20 + j]), fe[28 + j]);
        float res = __fadd_rn(__fadd_rn(__fadd_rn(po[0], po[1]), __fadd_rn(po[2], po[3])),
                              __fadd_rn(__fadd_rn(po[4], po[5]), __fadd_rn(po[6], po[7])));
        if (h) s_leaf[tid >> 1] = res;
        s_hist[tid] = 0;
        if (tid == 0) s_lcount = 0;
    }
    __syncthreads();
    if (tid < 64) {                                   // exact balanced tree over 128 leaves
        float v = __fadd_rn(s_leaf[2 * tid], s_leaf[2 * tid + 1]);
        #pragma unroll
        for (int o = 1; o < 64; o <<= 1) {
            float u = __shfl_xor(v, o, 64);
            v = __fadd_rn(v, u);
        }
        if (tid == 0) s_e2s = v;
    }
    __syncthreads();

    const float e2     = s_e2s;
    const int   nflip2 = (int)rintf(fabsf(e2));
    const bool  isup2  = (e2 < 0.0f);
    const float* val = isup2 ? s_uval : s_dval;
    const unsigned short* pos = isup2 ? s_upos : s_dpos;
    const signed char* cnv = isup2 ? s_ucn : s_dcn;

    // ---------- Phase C: stable top-nflip2 via 256-bucket histogram select ----------
    int   gg[4]; float vv[4]; int bb[4];
    #pragma unroll
    for (int m = 0; m < 4; ++m) {
        gg[m] = tid + m * NT;
        vv[m] = val[gg[m]];
        bb[m] = (vv[m] > 0.0f) ? bucketOf(vv[m]) : -1;
        if (bb[m] >= 0) atomicAdd(&s_hist[bb[m]], 1);
    }
    __syncthreads();
    if (tid < 64) {                                   // wave suffix scan of 256 bins
        int b0 = s_hist[4*tid], b1 = s_hist[4*tid+1], b2 = s_hist[4*tid+2], b3 = s_hist[4*tid+3];
        int s3 = b3, s2 = b2 + s3, s1 = b1 + s2, s0 = b0 + s1;
        int suf = s0;
        #pragma unroll
        for (int off = 1; off < 64; off <<= 1) {
            int o = __shfl_down(suf, off, 64);
            if (tid + off < 64) suf += o;
        }
        int above = suf - s0;
        s_hist[4*tid]   = s0 + above;
        s_hist[4*tid+1] = s1 + above;
        s_hist[4*tid+2] = s2 + above;
        s_hist[4*tid+3] = s3 + above;
    }
    __syncthreads();
    const int npos = s_hist[0];

    if (nflip2 > 0 && nflip2 <= npos) {
        {                                             // unique cutoff bucket
            int Tb  = s_hist[tid];
            int Tb1 = (tid < 255) ? s_hist[tid + 1] : 0;
            if (Tb >= nflip2 && Tb1 < nflip2) { s_seli[0] = tid; s_seli[1] = nflip2 - Tb1; }
        }
        __syncthreads();
        const int B = s_seli[0], m = s_seli[1];
        #pragma unroll
        for (int mm = 0; mm < 4; ++mm) {
            if (bb[mm] > B) s_r2[pos[gg[mm]]] = cnv[gg[mm]];
            else if (bb[mm] == B) {
                int ix = atomicAdd(&s_lcount, 1);
                if (ix < LCAP) { s_lv[ix] = vv[mm]; s_lg[ix] = (unsigned short)gg[mm]; }
            }
        }
        __syncthreads();
        const int L = s_lcount;
        if (L <= LCAP) {                              // exact stable rank in boundary bucket
            #pragma unroll
            for (int mm = 0; mm < 4; ++mm) {
                if (bb[mm] != B) continue;
                int rk = 0;
                for (int l = 0; l < L; ++l) {
                    float lv = s_lv[l]; int lg = s_lg[l];
                    rk += (int)((lv > vv[mm]) || ((lv == vv[mm]) && (lg < gg[mm])));
                }
                if (rk < m) s_r2[pos[gg[mm]]] = cnv[gg[mm]];
            }
        } else {                                      // degenerate tie flood
            #pragma unroll
            for (int mm = 0; mm < 4; ++mm) {
                if (bb[mm] != B) continue;
                int rk = 0;
                for (int j = 0; j < NGRP; ++j) {
                    float vj = val[j];
                    if (vj > 0.0f && bucketOf(vj) == B)
                        rk += (int)((vj > vv[mm]) || ((vj == vv[mm]) && (j < gg[mm])));
                }
                if (rk < m) s_r2[pos[gg[mm]]] = cnv[gg[mm]];
            }
        }
    } else if (nflip2 > npos) {
        // all positives flip; remainder spills into zero-priority dense slots by index
        #pragma unroll
        for (int mm = 0; mm < 4; ++mm)
            if (bb[mm] >= 0) s_r2[pos[gg[mm]]] = cnv[gg[mm]];
        __syncthreads();
        if (tid == 0) {
            int c = 0; const int extra = nflip2 - npos;
            for (int g = 0; g < NGRP && c < extra; ++g) {
                float r[9], err[9], q[9]; int nf1; bool up1; int li;
                replay_group(wrow + 9 * g, scale, zp, r, err, q, &nf1, &up1, &li);
                for (int j = 0; j < 9 && c < extra; ++j) {
                    int p = 9 * g + j;
                    if (val[g] > 0.0f && pos[g] == p) continue;   // already flipped above
                    float cnp;
                    if (isup2) { bool cu = (err[j] < 0.0f) && (q[j] < 7.0f);
                                 cnp = cu ? r[j] + 1.0f : r[j]; }
                    else       { bool cd = (err[j] > 0.0f) && (q[j] > -8.0f);
                                 cnp = cd ? r[j] - 1.0f : r[j]; }
                    if (nf1 > 0 && j == li && (up1 != isup2)) cnp = r[j];  // pass-1 revert
                    s_r2[p] = (signed char)clip16(__float2int_rn(cnp));
                    ++c;
                }
            }
        }
    }
    __syncthreads();

    // ---------- epilogue: LUT dequantize + fp32 store (bytes pre-clipped) ----------
    const int* r2i = reinterpret_cast<const int*>(s_r2);
    float4* o4 = reinterpret_cast<float4*>(out + (size_t)row * ROWLEN);
    #pragma unroll
    for (int k = 0; k < 9; ++k) {
        int i = tid + k * NT;
        int word = r2i[i];
        float4 o;
        o.x = s_lut[((int)(signed char)( word        & 0xff)) + 8];
        o.y = s_lut[((int)(signed char)((word >>  8) & 0xff)) + 8];
        o.z = s_lut[((int)(signed char)((word >> 16) & 0xff)) + 8];
        o.w = s_lut[((int)(signed char)((word >> 24) & 0xff)) + 8];
        o4[i] = o;
    }
}

extern "C" void kernel_launch(void* const* d_in, const int* in_sizes, int n_in,
                              void* d_out, int out_size, void* d_ws, size_t ws_size,
                              hipStream_t stream) {
    const float* w = (const float*)d_in[0];
    float* out = (float*)d_out;
    squant_kernel<<<dim3(NROW), dim3(NT), 0, stream>>>(w, out);
}